// Round 11
// baseline (371.391 us; speedup 1.0000x reference)
//
#include <hip/hip_runtime.h>
#include <hip/hip_fp16.h>

#define DIM 256

typedef float  f32x4 __attribute__((ext_vector_type(4)));
typedef int    i32x2 __attribute__((ext_vector_type(2)));
typedef _Float16 h16x8 __attribute__((ext_vector_type(8)));
typedef _Float16 h16x4 __attribute__((ext_vector_type(4)));

// Load 4 consecutive fp16 (8B) and upconvert.
__device__ inline float4 ld_h4(const _Float16* p) {
    const h16x4 h = *reinterpret_cast<const h16x4*>(p);
    return make_float4((float)h[0], (float)h[1], (float)h[2], (float)h[3]);
}

// ---------------------------------------------------------------------------
// W (fp32 [256][256]) -> Wh (fp16), one-shot.
// ---------------------------------------------------------------------------
__global__ __launch_bounds__(256) void cvt_w(
    const float* __restrict__ W, _Float16* __restrict__ Wh)
{
    const int i = blockIdx.x * 256 + threadIdx.x;   // grid = 256 blocks
    Wh[i] = (_Float16)W[i];
}

// ---------------------------------------------------------------------------
// LDS-staged MFMA GEMM + fused y2=x2 passthrough.
// hidden[i][j] = sum_k x2[i][k]*W[j][k] + b[j]  (fp16 out, fp32 accum)
// y2[i][k] = x2[i][k]  (stored from the A-preload registers: x2 read ONCE
//                       per pipeline; per (ks,row) the 4 kgrp lanes emit
//                       128B contiguous -> ok coalescing)
// 512 thr / 8 waves per block; wave w owns M-tile (blockIdx*8+w) = 16 rows.
// W fp16 staged in 64KB LDS per 128-col half, XOR-swizzled (same involution
// on write and read): byte = j*512 + (ko ^ ((j&7)<<4)).
// Fragment mapping identical to the HW-passed round-9 kernel.
// ---------------------------------------------------------------------------
__global__ __launch_bounds__(512) void gemm_mfma(
    const float* __restrict__ x2, const _Float16* __restrict__ Wh,
    const float* __restrict__ bias, _Float16* __restrict__ hidden,
    float* __restrict__ y2, int n, int n_tiles)
{
    __shared__ _Float16 Bl[128 * DIM];   // 64 KB

    const int wid  = threadIdx.x >> 6;
    const int lane = threadIdx.x & 63;
    const int tile = blockIdx.x * 8 + wid;
    const bool act = (tile < n_tiles);

    const int r16  = lane & 15;
    const int kgrp = lane >> 4;
    const int m0   = tile * 16;

    // ---- A preload: 8 k-steps, fp32 -> fp16 in regs; echo x2 -> y2 ----
    const bool rowok = act && (m0 + r16 < n);
    const int arow = rowok ? (m0 + r16) : 0;     // safe row; stores guarded
    const float* ap  = x2 + (size_t)arow * DIM;
    float*       yp  = y2 + (size_t)arow * DIM;

    h16x8 af[8];
    #pragma unroll
    for (int ks = 0; ks < 8; ++ks) {
        const int kb = ks * 32 + kgrp * 8;
        const float4 a01 = *reinterpret_cast<const float4*>(ap + kb);
        const float4 a23 = *reinterpret_cast<const float4*>(ap + kb + 4);
        if (rowok) {
            *reinterpret_cast<float4*>(yp + kb)     = a01;
            *reinterpret_cast<float4*>(yp + kb + 4) = a23;
        }
        h16x8 v;
        v[0] = (_Float16)a01.x; v[1] = (_Float16)a01.y;
        v[2] = (_Float16)a01.z; v[3] = (_Float16)a01.w;
        v[4] = (_Float16)a23.x; v[5] = (_Float16)a23.y;
        v[6] = (_Float16)a23.z; v[7] = (_Float16)a23.w;
        af[ks] = v;
    }

    f32x4 acc[16];
    #pragma unroll
    for (int t = 0; t < 16; ++t) acc[t] = (f32x4){0.f, 0.f, 0.f, 0.f};

    char* blb = reinterpret_cast<char*>(Bl);

    #pragma unroll
    for (int half = 0; half < 2; ++half) {
        __syncthreads();   // half=1: wait until all waves done reading half 0
        // ---- stage 128 cols x 256 k of Wh into LDS (swizzled) ----
        const char* src = reinterpret_cast<const char*>(Wh)
                        + (size_t)half * 128 * DIM * sizeof(_Float16);
        #pragma unroll
        for (int s = 0; s < 8; ++s) {
            const int c  = s * 512 + threadIdx.x;   // 0..4095
            const int j  = c >> 5;                  // 0..127 (col within half)
            const int ko = (c & 31) << 4;           // 0..496 step 16 (bytes)
            *reinterpret_cast<h16x8*>(blb + j * 512 + (ko ^ ((j & 7) << 4))) =
                *reinterpret_cast<const h16x8*>(src + j * 512 + ko);
        }
        __syncthreads();

        // ---- MFMA: 8 col-tiles x 8 k-steps from LDS ----
        #pragma unroll
        for (int jt = 0; jt < 8; ++jt) {
            const int j = jt * 16 + r16;            // col within half
            const int jsw = (j & 7) << 4;
            #pragma unroll
            for (int ks = 0; ks < 8; ++ks) {
                const int ko = ks * 64 + kgrp * 16;
                const h16x8 bf = *reinterpret_cast<const h16x8*>(
                    blb + j * 512 + (ko ^ jsw));
                acc[half * 8 + jt] = __builtin_amdgcn_mfma_f32_16x16x32_f16(
                    af[ks], bf, acc[half * 8 + jt], 0, 0, 0);
            }
        }
    }

    // ---- epilogue: bias + fp16 store ----
    if (act) {
        #pragma unroll
        for (int h = 0; h < 2; ++h) {
            #pragma unroll
            for (int jt = 0; jt < 8; ++jt) {
                const int col = h * 128 + jt * 16 + r16;
                const float bv = bias[col];
                #pragma unroll
                for (int r = 0; r < 4; ++r) {
                    const int grow = m0 + kgrp * 4 + r;
                    if (grow < n)
                        hidden[(size_t)grow * DIM + col] =
                            (_Float16)(acc[h * 8 + jt][r] + bv);
                }
            }
        }
    }
}

// ---------------------------------------------------------------------------
// CSR build: histogram -> exclusive scan (2-level) -> bucket fill
// ---------------------------------------------------------------------------
__global__ __launch_bounds__(256) void histo(
    const int* __restrict__ rows, int* __restrict__ deg, int n_edges)
{
    int e = blockIdx.x * 256 + threadIdx.x;
    const int stride = gridDim.x * 256;
    for (; e < n_edges; e += stride)
        atomicAdd(&deg[rows[e]], 1);
}

__global__ __launch_bounds__(256) void scan_block(
    const int* __restrict__ deg, int* __restrict__ offs,
    int* __restrict__ bsums, int n)
{
    __shared__ int s[256];
    const int gid = blockIdx.x * 256 + threadIdx.x;
    const int v = (gid < n) ? deg[gid] : 0;
    s[threadIdx.x] = v;
    __syncthreads();
    #pragma unroll
    for (int d = 1; d < 256; d <<= 1) {
        const int t = (threadIdx.x >= d) ? s[threadIdx.x - d] : 0;
        __syncthreads();
        s[threadIdx.x] += t;
        __syncthreads();
    }
    if (gid < n) offs[gid] = s[threadIdx.x] - v;     // exclusive within block
    if (threadIdx.x == 255) bsums[blockIdx.x] = s[255];
}

__global__ __launch_bounds__(256) void scan_sums(int* __restrict__ bsums, int nb)
{
    __shared__ int s[256];
    const int v = (threadIdx.x < nb) ? bsums[threadIdx.x] : 0;
    s[threadIdx.x] = v;
    __syncthreads();
    #pragma unroll
    for (int d = 1; d < 256; d <<= 1) {
        const int t = (threadIdx.x >= d) ? s[threadIdx.x - d] : 0;
        __syncthreads();
        s[threadIdx.x] += t;
        __syncthreads();
    }
    if (threadIdx.x < nb) bsums[threadIdx.x] = s[threadIdx.x] - v;  // exclusive
}

__global__ __launch_bounds__(256) void scan_add(
    int* __restrict__ offs, const int* __restrict__ bsums, int n, int n_edges)
{
    const int gid = blockIdx.x * 256 + threadIdx.x;
    if (gid < n) offs[gid] += bsums[blockIdx.x];
    if (gid == n - 1) offs[n] = n_edges;
}

__global__ __launch_bounds__(256) void bucket_fill(
    const int* __restrict__ rows, const int* __restrict__ cols,
    const float* __restrict__ vals, const int* __restrict__ offs,
    int* __restrict__ deg, int2* __restrict__ eb, int n_edges)
{
    int e = blockIdx.x * 256 + threadIdx.x;
    const int stride = gridDim.x * 256;
    for (; e < n_edges; e += stride) {
        const int r = rows[e];
        const int old = atomicSub(&deg[r], 1);
        const int pos = offs[r] + old - 1;
        eb[pos] = make_int2(cols[e], __float_as_int(vals[e]));
    }
}

// ---------------------------------------------------------------------------
// Aggregation (gather, no atomics) + fused y1 epilogue.
// One 64-lane wave per node; lane holds 4 of 256 features (fp16 gather, 8B).
// Unrolled x4, two accumulator chains. y2 copy now lives in gemm_mfma.
// y1 = relu(sum_e val*hidden[col]) + x1.
// ---------------------------------------------------------------------------
__global__ __launch_bounds__(256) void aggregate(
    const _Float16* __restrict__ hidden, const int* __restrict__ offs,
    const int2* __restrict__ eb,
    const float* __restrict__ x1, float* __restrict__ y1, int n)
{
    const int lane = threadIdx.x & 63;
    const int node = blockIdx.x * 4 + (threadIdx.x >> 6);
    if (node >= n) return;

    const int s = offs[node];
    const int e = offs[node + 1];
    const size_t fofs = (size_t)(lane * 4);

    float4 acc0 = make_float4(0.f, 0.f, 0.f, 0.f);
    float4 acc1 = make_float4(0.f, 0.f, 0.f, 0.f);

    int i = s;
    for (; i + 3 < e; i += 4) {
        const i32x2 p0 = __builtin_nontemporal_load(
            reinterpret_cast<const i32x2*>(&eb[i + 0]));
        const i32x2 p1 = __builtin_nontemporal_load(
            reinterpret_cast<const i32x2*>(&eb[i + 1]));
        const i32x2 p2 = __builtin_nontemporal_load(
            reinterpret_cast<const i32x2*>(&eb[i + 2]));
        const i32x2 p3 = __builtin_nontemporal_load(
            reinterpret_cast<const i32x2*>(&eb[i + 3]));
        const float4 h0 = ld_h4(hidden + (size_t)p0[0] * DIM + fofs);
        const float4 h1 = ld_h4(hidden + (size_t)p1[0] * DIM + fofs);
        const float4 h2 = ld_h4(hidden + (size_t)p2[0] * DIM + fofs);
        const float4 h3 = ld_h4(hidden + (size_t)p3[0] * DIM + fofs);
        const float v0 = __int_as_float(p0[1]);
        const float v1 = __int_as_float(p1[1]);
        const float v2 = __int_as_float(p2[1]);
        const float v3 = __int_as_float(p3[1]);
        acc0.x += v0 * h0.x + v1 * h1.x;
        acc0.y += v0 * h0.y + v1 * h1.y;
        acc0.z += v0 * h0.z + v1 * h1.z;
        acc0.w += v0 * h0.w + v1 * h1.w;
        acc1.x += v2 * h2.x + v3 * h3.x;
        acc1.y += v2 * h2.y + v3 * h3.y;
        acc1.z += v2 * h2.z + v3 * h3.z;
        acc1.w += v2 * h2.w + v3 * h3.w;
    }
    for (; i < e; ++i) {
        const i32x2 p0 = __builtin_nontemporal_load(
            reinterpret_cast<const i32x2*>(&eb[i]));
        const float v0 = __int_as_float(p0[1]);
        const float4 h0 = ld_h4(hidden + (size_t)p0[0] * DIM + fofs);
        acc0.x += v0 * h0.x;
        acc0.y += v0 * h0.y;
        acc0.z += v0 * h0.z;
        acc0.w += v0 * h0.w;
    }
    acc0.x += acc1.x; acc0.y += acc1.y; acc0.z += acc1.z; acc0.w += acc1.w;

    const size_t base = (size_t)node * DIM + fofs;
    const f32x4 a = __builtin_nontemporal_load(
        reinterpret_cast<const f32x4*>(x1 + base));
    f32x4 o;
    o[0] = fmaxf(acc0.x, 0.f) + a[0];
    o[1] = fmaxf(acc0.y, 0.f) + a[1];
    o[2] = fmaxf(acc0.z, 0.f) + a[2];
    o[3] = fmaxf(acc0.w, 0.f) + a[3];
    __builtin_nontemporal_store(o, reinterpret_cast<f32x4*>(y1 + base));
}

// ---------------------------------------------------------------------------
// Fallback path (atomic scatter) if ws_size is too small for CSR build.
// ---------------------------------------------------------------------------
__global__ __launch_bounds__(256) void edge_scatter(
    const _Float16* __restrict__ hidden,
    const int* __restrict__ rows, const int* __restrict__ cols,
    const float* __restrict__ vals,
    float* __restrict__ support, int n_edges)
{
    const int lane = threadIdx.x & 63;
    const int wslot = (blockIdx.x << 2) | (threadIdx.x >> 6);
    const int n_slots = gridDim.x << 2;
    for (int e = wslot; e < n_edges; e += n_slots) {
        const int r = rows[e];
        const int c = cols[e];
        const float v = vals[e];
        const float4 h = ld_h4(hidden + (size_t)c * DIM + lane * 4);
        float* sp = support + (size_t)r * DIM + lane * 4;
        atomicAdd(sp + 0, v * h.x);
        atomicAdd(sp + 1, v * h.y);
        atomicAdd(sp + 2, v * h.z);
        atomicAdd(sp + 3, v * h.w);
    }
}

__global__ __launch_bounds__(256) void epilogue(
    const float* __restrict__ x1, float* __restrict__ out_y1, size_t total4)
{
    const float4* x1v = reinterpret_cast<const float4*>(x1);
    float4* y1v = reinterpret_cast<float4*>(out_y1);
    size_t i = (size_t)blockIdx.x * blockDim.x + threadIdx.x;
    const size_t stride = (size_t)gridDim.x * blockDim.x;
    for (; i < total4; i += stride) {
        float4 s = y1v[i];
        float4 a = x1v[i];
        float4 o;
        o.x = fmaxf(s.x, 0.f) + a.x;
        o.y = fmaxf(s.y, 0.f) + a.y;
        o.z = fmaxf(s.z, 0.f) + a.z;
        o.w = fmaxf(s.w, 0.f) + a.w;
        y1v[i] = o;
    }
}

extern "C" void kernel_launch(void* const* d_in, const int* in_sizes, int n_in,
                              void* d_out, int out_size, void* d_ws, size_t ws_size,
                              hipStream_t stream) {
    const float* x1   = (const float*)d_in[0];
    const float* x2   = (const float*)d_in[1];
    const int*   rows = (const int*)d_in[2];
    const int*   cols = (const int*)d_in[3];
    const float* vals = (const float*)d_in[4];
    const float* W    = (const float*)d_in[5];
    const float* bias = (const float*)d_in[6];

    const int n_nodes = in_sizes[0] / DIM;
    const int n_edges = in_sizes[2];
    const int nb = (n_nodes + 255) / 256;   // scan blocks (<=256 required)

    float* out     = (float*)d_out;
    float* out_y2  = out;                              // y2 = x2
    float* out_y1  = out + (size_t)n_nodes * DIM;      // y1

    // workspace layout (hidden fp16, Wh fp16)
    char* ws = (char*)d_ws;
    _Float16* hidden = (_Float16*)ws;
    size_t off = (size_t)n_nodes * DIM * sizeof(_Float16);
    _Float16* Wh = (_Float16*)(ws + off); off += (size_t)DIM * DIM * sizeof(_Float16);
    int* offs  = (int*)(ws + off);  off += (size_t)(n_nodes + 1) * sizeof(int);
    int* deg   = (int*)(ws + off);  off += (size_t)n_nodes * sizeof(int);
    int* bsums = (int*)(ws + off);  off += 256 * sizeof(int);
    off = (off + 15) & ~(size_t)15;
    int2* eb   = (int2*)(ws + off); off += (size_t)n_edges * sizeof(int2);
    const bool csr_ok = (off <= ws_size) && (nb <= 256);

    // 1) Wh = fp16(W); hidden = x2 @ W^T + b; y2 = x2 (fused passthrough)
    cvt_w<<<DIM * DIM / 256, 256, 0, stream>>>(W, Wh);
    const int n_tiles = (n_nodes + 15) / 16;
    gemm_mfma<<<(n_tiles + 7) / 8, 512, 0, stream>>>(
        x2, Wh, bias, hidden, out_y2, n_nodes, n_tiles);

    if (csr_ok) {
        // 2) CSR build
        (void)hipMemsetAsync(deg, 0, (size_t)n_nodes * sizeof(int), stream);
        histo<<<(n_edges + 255) / 256, 256, 0, stream>>>(rows, deg, n_edges);
        scan_block<<<nb, 256, 0, stream>>>(deg, offs, bsums, n_nodes);
        scan_sums<<<1, 256, 0, stream>>>(bsums, nb);
        scan_add<<<nb, 256, 0, stream>>>(offs, bsums, n_nodes, n_edges);
        bucket_fill<<<(n_edges + 255) / 256, 256, 0, stream>>>(
            rows, cols, vals, offs, deg, eb, n_edges);

        // 3) gather-aggregate + fused y1 epilogue
        aggregate<<<(n_nodes + 3) / 4, 256, 0, stream>>>(
            hidden, offs, eb, x1, out_y1, n_nodes);
    } else {
        // fallback: atomic scatter into out_y1 (used as support accumulator)
        (void)hipMemsetAsync(out_y1, 0, (size_t)n_nodes * DIM * sizeof(float), stream);
        edge_scatter<<<2048, 256, 0, stream>>>(hidden, rows, cols, vals,
                                               out_y1, n_edges);
        const size_t total4 = (size_t)n_nodes * DIM / 4;
        epilogue<<<2048, 256, 0, stream>>>(x1, out_y1, total4);
    }
}

// Round 12
// 328.302 us; speedup vs baseline: 1.1312x; 1.1312x over previous
//
#include <hip/hip_runtime.h>
#include <hip/hip_fp16.h>

#define DIM 256
#define SLOTS 48   // fixed bucket capacity per node; P(deg>48 | E/N=16) ~ 3e-11

typedef float  f32x4 __attribute__((ext_vector_type(4)));
typedef int    i32x2 __attribute__((ext_vector_type(2)));
typedef _Float16 h16x8 __attribute__((ext_vector_type(8)));
typedef _Float16 h16x4 __attribute__((ext_vector_type(4)));

// Load 4 consecutive fp16 (8B) and upconvert.
__device__ inline float4 ld_h4(const _Float16* p) {
    const h16x4 h = *reinterpret_cast<const h16x4*>(p);
    return make_float4((float)h[0], (float)h[1], (float)h[2], (float)h[3]);
}

// ---------------------------------------------------------------------------
// W (fp32 [256][256]) -> Wh (fp16), one-shot.
// ---------------------------------------------------------------------------
__global__ __launch_bounds__(256) void cvt_w(
    const float* __restrict__ W, _Float16* __restrict__ Wh)
{
    const int i = blockIdx.x * 256 + threadIdx.x;   // grid = 256 blocks
    Wh[i] = (_Float16)W[i];
}

// ---------------------------------------------------------------------------
// LDS-staged MFMA GEMM + fused y2=x2 passthrough (unchanged from R11, passed).
// ---------------------------------------------------------------------------
__global__ __launch_bounds__(512) void gemm_mfma(
    const float* __restrict__ x2, const _Float16* __restrict__ Wh,
    const float* __restrict__ bias, _Float16* __restrict__ hidden,
    float* __restrict__ y2, int n, int n_tiles)
{
    __shared__ _Float16 Bl[128 * DIM];   // 64 KB

    const int wid  = threadIdx.x >> 6;
    const int lane = threadIdx.x & 63;
    const int tile = blockIdx.x * 8 + wid;
    const bool act = (tile < n_tiles);

    const int r16  = lane & 15;
    const int kgrp = lane >> 4;
    const int m0   = tile * 16;

    const bool rowok = act && (m0 + r16 < n);
    const int arow = rowok ? (m0 + r16) : 0;
    const float* ap = x2 + (size_t)arow * DIM;
    float*       yp = y2 + (size_t)arow * DIM;

    h16x8 af[8];
    #pragma unroll
    for (int ks = 0; ks < 8; ++ks) {
        const int kb = ks * 32 + kgrp * 8;
        const float4 a01 = *reinterpret_cast<const float4*>(ap + kb);
        const float4 a23 = *reinterpret_cast<const float4*>(ap + kb + 4);
        if (rowok) {
            *reinterpret_cast<float4*>(yp + kb)     = a01;
            *reinterpret_cast<float4*>(yp + kb + 4) = a23;
        }
        h16x8 v;
        v[0] = (_Float16)a01.x; v[1] = (_Float16)a01.y;
        v[2] = (_Float16)a01.z; v[3] = (_Float16)a01.w;
        v[4] = (_Float16)a23.x; v[5] = (_Float16)a23.y;
        v[6] = (_Float16)a23.z; v[7] = (_Float16)a23.w;
        af[ks] = v;
    }

    f32x4 acc[16];
    #pragma unroll
    for (int t = 0; t < 16; ++t) acc[t] = (f32x4){0.f, 0.f, 0.f, 0.f};

    char* blb = reinterpret_cast<char*>(Bl);

    #pragma unroll
    for (int half = 0; half < 2; ++half) {
        __syncthreads();
        const char* src = reinterpret_cast<const char*>(Wh)
                        + (size_t)half * 128 * DIM * sizeof(_Float16);
        #pragma unroll
        for (int s = 0; s < 8; ++s) {
            const int c  = s * 512 + threadIdx.x;   // 0..4095
            const int j  = c >> 5;                  // 0..127
            const int ko = (c & 31) << 4;           // bytes
            *reinterpret_cast<h16x8*>(blb + j * 512 + (ko ^ ((j & 7) << 4))) =
                *reinterpret_cast<const h16x8*>(src + j * 512 + ko);
        }
        __syncthreads();

        #pragma unroll
        for (int jt = 0; jt < 8; ++jt) {
            const int j = jt * 16 + r16;
            const int jsw = (j & 7) << 4;
            #pragma unroll
            for (int ks = 0; ks < 8; ++ks) {
                const int ko = ks * 64 + kgrp * 16;
                const h16x8 bf = *reinterpret_cast<const h16x8*>(
                    blb + j * 512 + (ko ^ jsw));
                acc[half * 8 + jt] = __builtin_amdgcn_mfma_f32_16x16x32_f16(
                    af[ks], bf, acc[half * 8 + jt], 0, 0, 0);
            }
        }
    }

    if (act) {
        #pragma unroll
        for (int h = 0; h < 2; ++h) {
            #pragma unroll
            for (int jt = 0; jt < 8; ++jt) {
                const int col = h * 128 + jt * 16 + r16;
                const float bv = bias[col];
                #pragma unroll
                for (int r = 0; r < 4; ++r) {
                    const int grow = m0 + kgrp * 4 + r;
                    if (grow < n)
                        hidden[(size_t)grow * DIM + col] =
                            (_Float16)(acc[h * 8 + jt][r] + bv);
                }
            }
        }
    }
}

// ---------------------------------------------------------------------------
// Fixed-slot bucket fill (replaces histo + 3 scans + bucket_fill).
// cnt zeroed beforehand; slot = (col, val) packed int2. Overflow (deg>SLOTS,
// never in practice) appends (r, col, val, 0) to ovf for exact correctness.
// ---------------------------------------------------------------------------
__global__ __launch_bounds__(256) void fill(
    const int* __restrict__ rows, const int* __restrict__ cols,
    const float* __restrict__ vals,
    int* __restrict__ cnt, int2* __restrict__ slots,
    int4* __restrict__ ovf, int* __restrict__ ocnt, int n_edges)
{
    int e = blockIdx.x * 256 + threadIdx.x;
    const int stride = gridDim.x * 256;
    for (; e < n_edges; e += stride) {
        const int r = rows[e];
        const int c = atomicAdd(&cnt[r], 1);
        if (c < SLOTS) {
            slots[(size_t)r * SLOTS + c] = make_int2(cols[e], __float_as_int(vals[e]));
        } else {
            const int o = atomicAdd(ocnt, 1);
            ovf[o] = make_int4(r, cols[e], __float_as_int(vals[e]), 0);
        }
    }
}

// ---------------------------------------------------------------------------
// Aggregation (gather, no atomics) + fused y1 epilogue.
// One 64-lane wave per node; lane holds 4 of 256 features (fp16 gather, 8B).
// Reads its fixed-slot bucket (contiguous); overflow scan only if this node
// overflowed (never in practice). y1 = relu(sum val*hidden[col]) + x1.
// ---------------------------------------------------------------------------
__global__ __launch_bounds__(256) void aggregate(
    const _Float16* __restrict__ hidden, const int* __restrict__ cnt,
    const int2* __restrict__ slots, const int4* __restrict__ ovf,
    const int* __restrict__ ocnt,
    const float* __restrict__ x1, float* __restrict__ y1, int n)
{
    const int lane = threadIdx.x & 63;
    const int node = blockIdx.x * 4 + (threadIdx.x >> 6);
    if (node >= n) return;

    const int m  = cnt[node];
    const int mm = (m < SLOTS) ? m : SLOTS;
    const int2* sp = slots + (size_t)node * SLOTS;
    const size_t fofs = (size_t)(lane * 4);

    float4 acc0 = make_float4(0.f, 0.f, 0.f, 0.f);
    float4 acc1 = make_float4(0.f, 0.f, 0.f, 0.f);

    int i = 0;
    for (; i + 3 < mm; i += 4) {
        const i32x2 p0 = __builtin_nontemporal_load(
            reinterpret_cast<const i32x2*>(sp + i + 0));
        const i32x2 p1 = __builtin_nontemporal_load(
            reinterpret_cast<const i32x2*>(sp + i + 1));
        const i32x2 p2 = __builtin_nontemporal_load(
            reinterpret_cast<const i32x2*>(sp + i + 2));
        const i32x2 p3 = __builtin_nontemporal_load(
            reinterpret_cast<const i32x2*>(sp + i + 3));
        const float4 h0 = ld_h4(hidden + (size_t)p0[0] * DIM + fofs);
        const float4 h1 = ld_h4(hidden + (size_t)p1[0] * DIM + fofs);
        const float4 h2 = ld_h4(hidden + (size_t)p2[0] * DIM + fofs);
        const float4 h3 = ld_h4(hidden + (size_t)p3[0] * DIM + fofs);
        const float v0 = __int_as_float(p0[1]);
        const float v1 = __int_as_float(p1[1]);
        const float v2 = __int_as_float(p2[1]);
        const float v3 = __int_as_float(p3[1]);
        acc0.x += v0 * h0.x + v1 * h1.x;
        acc0.y += v0 * h0.y + v1 * h1.y;
        acc0.z += v0 * h0.z + v1 * h1.z;
        acc0.w += v0 * h0.w + v1 * h1.w;
        acc1.x += v2 * h2.x + v3 * h3.x;
        acc1.y += v2 * h2.y + v3 * h3.y;
        acc1.z += v2 * h2.z + v3 * h3.z;
        acc1.w += v2 * h2.w + v3 * h3.w;
    }
    for (; i < mm; ++i) {
        const i32x2 p0 = __builtin_nontemporal_load(
            reinterpret_cast<const i32x2*>(sp + i));
        const float v0 = __int_as_float(p0[1]);
        const float4 h0 = ld_h4(hidden + (size_t)p0[0] * DIM + fofs);
        acc0.x += v0 * h0.x;
        acc0.y += v0 * h0.y;
        acc0.z += v0 * h0.z;
        acc0.w += v0 * h0.w;
    }

    if (m > SLOTS) {                 // pathological only; exact correctness
        const int no = *ocnt;
        for (int k = 0; k < no; ++k) {
            const int4 t = ovf[k];
            if (t.x == node) {
                const float v = __int_as_float(t.z);
                const float4 h = ld_h4(hidden + (size_t)t.y * DIM + fofs);
                acc0.x += v * h.x;
                acc0.y += v * h.y;
                acc0.z += v * h.z;
                acc0.w += v * h.w;
            }
        }
    }

    acc0.x += acc1.x; acc0.y += acc1.y; acc0.z += acc1.z; acc0.w += acc1.w;

    const size_t base = (size_t)node * DIM + fofs;
    const f32x4 a = __builtin_nontemporal_load(
        reinterpret_cast<const f32x4*>(x1 + base));
    f32x4 o;
    o[0] = fmaxf(acc0.x, 0.f) + a[0];
    o[1] = fmaxf(acc0.y, 0.f) + a[1];
    o[2] = fmaxf(acc0.z, 0.f) + a[2];
    o[3] = fmaxf(acc0.w, 0.f) + a[3];
    __builtin_nontemporal_store(o, reinterpret_cast<f32x4*>(y1 + base));
}

// ---------------------------------------------------------------------------
// Fallback path (atomic scatter) if ws_size is too small.
// ---------------------------------------------------------------------------
__global__ __launch_bounds__(256) void edge_scatter(
    const _Float16* __restrict__ hidden,
    const int* __restrict__ rows, const int* __restrict__ cols,
    const float* __restrict__ vals,
    float* __restrict__ support, int n_edges)
{
    const int lane = threadIdx.x & 63;
    const int wslot = (blockIdx.x << 2) | (threadIdx.x >> 6);
    const int n_slots = gridDim.x << 2;
    for (int e = wslot; e < n_edges; e += n_slots) {
        const int r = rows[e];
        const int c = cols[e];
        const float v = vals[e];
        const float4 h = ld_h4(hidden + (size_t)c * DIM + lane * 4);
        float* sp = support + (size_t)r * DIM + lane * 4;
        atomicAdd(sp + 0, v * h.x);
        atomicAdd(sp + 1, v * h.y);
        atomicAdd(sp + 2, v * h.z);
        atomicAdd(sp + 3, v * h.w);
    }
}

__global__ __launch_bounds__(256) void epilogue(
    const float* __restrict__ x1, float* __restrict__ out_y1, size_t total4)
{
    const float4* x1v = reinterpret_cast<const float4*>(x1);
    float4* y1v = reinterpret_cast<float4*>(out_y1);
    size_t i = (size_t)blockIdx.x * blockDim.x + threadIdx.x;
    const size_t stride = (size_t)gridDim.x * blockDim.x;
    for (; i < total4; i += stride) {
        float4 s = y1v[i];
        float4 a = x1v[i];
        float4 o;
        o.x = fmaxf(s.x, 0.f) + a.x;
        o.y = fmaxf(s.y, 0.f) + a.y;
        o.z = fmaxf(s.z, 0.f) + a.z;
        o.w = fmaxf(s.w, 0.f) + a.w;
        y1v[i] = o;
    }
}

extern "C" void kernel_launch(void* const* d_in, const int* in_sizes, int n_in,
                              void* d_out, int out_size, void* d_ws, size_t ws_size,
                              hipStream_t stream) {
    const float* x1   = (const float*)d_in[0];
    const float* x2   = (const float*)d_in[1];
    const int*   rows = (const int*)d_in[2];
    const int*   cols = (const int*)d_in[3];
    const float* vals = (const float*)d_in[4];
    const float* W    = (const float*)d_in[5];
    const float* bias = (const float*)d_in[6];

    const int n_nodes = in_sizes[0] / DIM;
    const int n_edges = in_sizes[2];

    float* out     = (float*)d_out;
    float* out_y2  = out;                              // y2 = x2
    float* out_y1  = out + (size_t)n_nodes * DIM;      // y1

    // workspace layout: hidden 25.6MB | Wh 128KB | cnt+ocnt | slots 19.2MB |
    // ovf 12.8MB  -> ~57.9MB total (< 58.0MB proven available in R7)
    char* ws = (char*)d_ws;
    _Float16* hidden = (_Float16*)ws;
    size_t off = (size_t)n_nodes * DIM * sizeof(_Float16);
    _Float16* Wh = (_Float16*)(ws + off); off += (size_t)DIM * DIM * sizeof(_Float16);
    int* cnt  = (int*)(ws + off);  off += (size_t)n_nodes * sizeof(int);
    int* ocnt = (int*)(ws + off);  off += sizeof(int);
    off = (off + 15) & ~(size_t)15;
    int2* slots = (int2*)(ws + off); off += (size_t)n_nodes * SLOTS * sizeof(int2);
    int4* ovf   = (int4*)(ws + off); off += (size_t)n_edges * sizeof(int4);
    const bool csr_ok = (off <= ws_size);

    // 1) Wh = fp16(W); hidden = x2 @ W^T + b; y2 = x2 (fused passthrough)
    cvt_w<<<DIM * DIM / 256, 256, 0, stream>>>(W, Wh);
    const int n_tiles = (n_nodes + 15) / 16;
    gemm_mfma<<<(n_tiles + 7) / 8, 512, 0, stream>>>(
        x2, Wh, bias, hidden, out_y2, n_nodes, n_tiles);

    if (csr_ok) {
        // 2) zero counters, fill fixed-slot buckets (single pass, no scan)
        (void)hipMemsetAsync(cnt, 0, ((size_t)n_nodes + 1) * sizeof(int), stream);
        fill<<<(n_edges + 255) / 256, 256, 0, stream>>>(
            rows, cols, vals, cnt, slots, ovf, ocnt, n_edges);

        // 3) gather-aggregate + fused y1 epilogue
        aggregate<<<(n_nodes + 3) / 4, 256, 0, stream>>>(
            hidden, cnt, slots, ovf, ocnt, x1, out_y1, n_nodes);
    } else {
        // fallback: atomic scatter into out_y1 (used as support accumulator)
        (void)hipMemsetAsync(out_y1, 0, (size_t)n_nodes * DIM * sizeof(float), stream);
        edge_scatter<<<2048, 256, 0, stream>>>(hidden, rows, cols, vals,
                                               out_y1, n_edges);
        const size_t total4 = (size_t)n_nodes * DIM / 4;
        epilogue<<<2048, 256, 0, stream>>>(x1, out_y1, total4);
    }
}